// Round 4
// baseline (244.428 us; speedup 1.0000x reference)
//
#include <hip/hip_runtime.h>
#include <math.h>

// x: [B=32, T=2048, H=512] fp32, alpha: [H,3] -> out [B,T,H] fp32.
// Per-feature softmax blend of 3 sliding-window z-scores (w=5,10,20),
// replicate-padded at front, unbiased std, sd clamped at 1e-4.
//
// R7 design: register shift-ring, float2/thread, NO LDS, PLAIN stores.
// R6 post-mortem: all R3-R6 variants pinned at ~92us. Shared culprit:
// __builtin_nontemporal_store every step. NT stores bypass L2/L3 and retire
// at HBM, holding vmcnt high; s_waitcnt vmcnt(N) counts loads AND stores, so
// every per-step load-use wait also waited ~1 HBM latency for the previous
// store to drain. Fix: plain stores (retire at L2) + CHUNK=32 -> 2048 blocks
// = 8 blocks/CU = 32 waves/CU, so TLP alone covers latency even at load
// depth 1 (32 waves x 512B = 16KB in flight/CU -> >6 TB/s by Little's law).

typedef float v2f __attribute__((ext_vector_type(2)));

#define BB 32
#define TT 2048
#define HH 512
#define H2 256      // float2 columns
#define CHUNK 32    // t-rows per block: groups 20+12

__constant__ constexpr float INV_W_[3]   = {0.2f, 0.1f, 0.05f};
__constant__ constexpr float INV_WM1_[3] = {0.25f, 1.0f/9.0f, 1.0f/19.0f};

static __device__ __forceinline__ v2f vmax2(v2f a, v2f b) { return __builtin_elementwise_max(a, b); }
static __device__ __forceinline__ v2f vmin2(v2f a, v2f b) { return __builtin_elementwise_min(a, b); }
static __device__ __forceinline__ v2f vrsq2(v2f a) {
    v2f r; r.x = __builtin_amdgcn_rsqf(a.x); r.y = __builtin_amdgcn_rsqf(a.y); return r;
}

static __device__ __forceinline__ v2f step_compute(v2f v, v2f o5, v2f o10, v2f o20,
                                                   v2f (&S)[3], v2f (&S2)[3],
                                                   const v2f (&aw)[3]) {
    const v2f od[3] = {o5, o10, o20};
    const v2f vv = v * v;
    v2f acc = {0.f, 0.f};
    #pragma unroll
    for (int i = 0; i < 3; ++i) {
        S[i]  += v - od[i];
        S2[i] += vv - od[i] * od[i];
        const v2f mu  = S[i] * INV_W_[i];
        const v2f var = vmax2((S2[i] - S[i] * mu) * INV_WM1_[i], v2f{0.f, 0.f});
        const v2f rs  = vmin2(vrsq2(var), v2f{1e4f, 1e4f});
        acc += (v - mu) * rs * aw[i];
    }
    return acc;
}

// One group of NSTEP (<=20) t-steps starting at row `base`.
// IN[g] = x[base+g] (loaded by previous group); HIST[k] = x[base-20+k].
// Issues NLOAD loads for the NEXT group into HIST[g] (rows base+20+g),
// each right after HIST[g]'s last read (o20 at step g). All indices static.
template<int NSTEP, int NLOAD>
static __device__ __forceinline__ void run_group(const v2f* __restrict__ px,
                                                 v2f* __restrict__ po, int base,
                                                 v2f (&IN)[20], v2f (&HIST)[20],
                                                 v2f (&S)[3], v2f (&S2)[3],
                                                 const v2f (&aw)[3]) {
    #pragma unroll
    for (int g = 0; g < NSTEP; ++g) {
        const v2f v   = IN[g];
        const v2f o20 = HIST[g];
        const v2f o5  = (g >= 5)  ? IN[g - 5]  : HIST[g + 15];
        const v2f o10 = (g >= 10) ? IN[g - 10] : HIST[g + 10];
        const v2f acc = step_compute(v, o5, o10, o20, S, S2, aw);
        po[(size_t)(base + g) * H2] = acc;
        if (g < NLOAD) HIST[g] = px[(size_t)(base + 20 + g) * H2];
    }
}

__global__ __launch_bounds__(256, 4) void fan_kernel(const float* __restrict__ x,
                                                     const float* __restrict__ alpha,
                                                     float* __restrict__ out) {
    const int tid = threadIdx.x;              // float2 column index
    const int t0  = blockIdx.x * CHUNK;
    const int b   = blockIdx.y;

    // per-feature softmax over the 3 windows (2 channels per thread)
    v2f aw[3];
    {
        const v2f* a2 = (const v2f*)alpha + 3 * tid;   // 6 contiguous floats
        v2f A0 = a2[0], A1 = a2[1], A2 = a2[2];
        float f[2][3] = {{A0.x, A0.y, A1.x}, {A1.y, A2.x, A2.y}};
        float w[2][3];
        #pragma unroll
        for (int j = 0; j < 2; ++j) {
            float mx = fmaxf(f[j][0], fmaxf(f[j][1], f[j][2]));
            float e0 = __expf(f[j][0] - mx);
            float e1 = __expf(f[j][1] - mx);
            float e2 = __expf(f[j][2] - mx);
            float inv = 1.0f / (e0 + e1 + e2);
            w[j][0] = e0 * inv; w[j][1] = e1 * inv; w[j][2] = e2 * inv;
        }
        #pragma unroll
        for (int i = 0; i < 3; ++i) { aw[i].x = w[0][i]; aw[i].y = w[1][i]; }
    }

    const v2f* __restrict__ px = (const v2f*)x + (size_t)b * TT * H2 + tid;
    v2f*       __restrict__ po = (v2f*)out     + (size_t)b * TT * H2 + tid;

    v2f S[3]  = {{0,0},{0,0},{0,0}};
    v2f S2[3] = {{0,0},{0,0},{0,0}};
    v2f A[20], Bv[20];   // register shift-ring, role-swapped per group

    if (t0 == 0) {
        constexpr int W_[3] = {5, 10, 20};
        // ---- pass 1: prescan rows [0,20) into A, prefix checkpoints at 5,10,15,20
        v2f P = {0,0}, Q = {0,0};
        v2f CP[4], CQ[4];
        #pragma unroll
        for (int t = 0; t < 20; ++t) {
            v2f v = px[(size_t)t * H2];
            A[t] = v;
            P += v; Q += v * v;
            if (t == 4 || t == 9 || t == 14 || t == 19) {
                const int ci = (t + 1) / 5 - 1;
                CP[ci] = P; CQ[ci] = Q;
            }
        }
        // replicate stats: windows [0,w-1] -> checkpoints 5,10,20 (idx 0,1,3)
        v2f rmu[3], rrsd[3];
        constexpr int CMAP[3] = {0, 1, 3};
        #pragma unroll
        for (int i = 0; i < 3; ++i) {
            v2f s = CP[CMAP[i]], s2 = CQ[CMAP[i]];
            v2f mu  = s * INV_W_[i];
            v2f var = vmax2((s2 - s * mu) * INV_WM1_[i], v2f{0.f, 0.f});
            rmu[i]  = mu;
            rrsd[i] = vmin2(vrsq2(var), v2f{1e4f, 1e4f});
        }
        // issue main-group loads (rows 20..31) -> hidden under pass 2
        #pragma unroll
        for (int g = 0; g < 12; ++g) Bv[g] = px[(size_t)(20 + g) * H2];
        // ---- pass 2: outputs [0,20) from register ring, running clipped sums
        #pragma unroll
        for (int t = 0; t < 20; ++t) {
            v2f v = A[t];
            v2f acc = {0.f, 0.f};
            #pragma unroll
            for (int i = 0; i < 3; ++i) {
                if (t >= W_[i]) {
                    v2f o = A[t - W_[i]];
                    S[i]  += v - o;
                    S2[i] += v * v - o * o;
                } else {
                    S[i]  += v;
                    S2[i] += v * v;
                }
                v2f mu, rs;
                if (t >= W_[i] - 1) {
                    mu = S[i] * INV_W_[i];
                    v2f var = vmax2((S2[i] - S[i] * mu) * INV_WM1_[i], v2f{0.f, 0.f});
                    rs = vmin2(vrsq2(var), v2f{1e4f, 1e4f});
                } else {
                    mu = rmu[i]; rs = rrsd[i];
                }
                acc += (v - mu) * rs * aw[i];
            }
            po[(size_t)t * H2] = acc;
        }
        // entry sums for t=20: S_w = P20 - P(20-w)
        S[0] = CP[3] - CP[2];  S2[0] = CQ[3] - CQ[2];
        S[1] = CP[3] - CP[1];  S2[1] = CQ[3] - CQ[1];
        S[2] = CP[3];          S2[2] = CQ[3];

        // main: rows [20,32). A = rows 0..19, Bv = rows 20..31 (in flight)
        run_group<12, 0>(px, po, 20, Bv, A, S, S2, aw);
    } else {
        // ---- interior warm-up: rows [t0-20, t0) -> A + clipped sums
        #pragma unroll
        for (int k = 0; k < 20; ++k) {
            v2f v = px[(size_t)(t0 - 20 + k) * H2];
            A[k] = v;
            if (k >= 15) { S[0] += v; S2[0] += v * v; }   // last 5
            if (k >= 10) { S[1] += v; S2[1] += v * v; }   // last 10
            {             S[2] += v; S2[2] += v * v; }    // last 20
        }
        // issue first main-group loads (rows t0..t0+19)
        #pragma unroll
        for (int g = 0; g < 20; ++g) Bv[g] = px[(size_t)(t0 + g) * H2];

        run_group<20, 12>(px, po, t0,      Bv, A,  S, S2, aw);  // loads A[0..11] <- t0+20..31
        run_group<12,  0>(px, po, t0 + 20, A,  Bv, S, S2, aw);
    }
}

extern "C" void kernel_launch(void* const* d_in, const int* in_sizes, int n_in,
                              void* d_out, int out_size, void* d_ws, size_t ws_size,
                              hipStream_t stream) {
    const float* x     = (const float*)d_in[0];
    const float* alpha = (const float*)d_in[1];
    float*       out   = (float*)d_out;

    dim3 grid(TT / CHUNK, BB);   // 64 x 32 = 2048 blocks -> 8 blocks/CU
    dim3 block(H2);              // one thread per float2 column
    fan_kernel<<<grid, block, 0, stream>>>(x, alpha, out);
}